// Round 15
// baseline (452.138 us; speedup 1.0000x reference)
//
#include <hip/hip_runtime.h>
#include <math.h>

typedef __bf16 bf16_t;
typedef bf16_t bf16x8 __attribute__((ext_vector_type(8)));
typedef bf16_t bf16x2 __attribute__((ext_vector_type(2)));
typedef float  f32x16 __attribute__((ext_vector_type(16)));
typedef unsigned u32x4 __attribute__((ext_vector_type(4)));

constexpr int H = 64, W = 64, Q = 65536;
constexpr int WP = 272;   // padded K: 256 data + col256 = bias + zeros to 272

// ---------------- prep kernels ----------------

// src [Crows][4096] f32 -> dst [4096][Crows] bf16
__global__ void transpose_cvt_kernel(const float* __restrict__ src, bf16_t* __restrict__ dst, int Crows) {
    __shared__ float tile[32][33];
    int bx = blockIdx.x * 32;
    int by = blockIdx.y * 32;
    int tx = threadIdx.x & 31;
    int ty = threadIdx.x >> 5;
#pragma unroll
    for (int i = 0; i < 4; i++)
        tile[ty + i * 8][tx] = src[(by + ty + i * 8) * 4096 + bx + tx];
    __syncthreads();
#pragma unroll
    for (int i = 0; i < 4; i++)
        dst[(bx + ty + i * 8) * Crows + by + tx] = (bf16_t)tile[tx][ty + i * 8];
}

__global__ void pack_tab_kernel(const float* __restrict__ wcf, const float* __restrict__ wph,
                                float4* __restrict__ wtab) {
    int k = threadIdx.x;
    float4 v;
    v.x = wcf[k * 2 + 0]; v.y = wcf[k * 2 + 1];
    v.z = wph[k * 2 + 0]; v.w = wph[k * 2 + 1];
    wtab[k] = v;
}

// W matrices padded to [256][272] with bias folded at col 256; w3 padded to [32][272]
__global__ void build_wp_kernel(const float* __restrict__ w1, const float* __restrict__ b1,
                                const float* __restrict__ w2, const float* __restrict__ b2,
                                const float* __restrict__ w3, const float* __restrict__ b3,
                                bf16_t* __restrict__ w1p, bf16_t* __restrict__ w2p,
                                bf16_t* __restrict__ w3p) {
    int n = threadIdx.x;  // 256
    for (int k = 0; k < WP; k++) {
        float v1 = (k < 256) ? w1[n * 256 + k] : ((k == 256) ? b1[n] : 0.f);
        float v2 = (k < 256) ? w2[n * 256 + k] : ((k == 256) ? b2[n] : 0.f);
        w1p[n * WP + k] = (bf16_t)v1;
        w2p[n * WP + k] = (bf16_t)v2;
    }
    if (n < 32) {
        for (int k = 0; k < WP; k++) {
            float v = 0.f;
            if (n < 3) v = (k < 256) ? w3[n * 256 + k] : ((k == 256) ? b3[n] : 0.f);
            w3p[n * WP + k] = (bf16_t)v;
        }
    }
}

// ---------------- main kernel: barrier-free M-split, 32 rows per wave ----------------

__device__ __forceinline__ unsigned pk2(float a, float b) {
    bf16x2 p; p[0] = (bf16_t)a; p[1] = (bf16_t)b;
    return __builtin_bit_cast(unsigned, p);
}

// one 256->256 layer: acc[nf] (16 f32) = sum_kb mfma(Wfrag[nf][kb], Xfrag[kb])
// D[i=n][j=m]: acc[nf][r] = h[m = l31][n = nf*32 + (r&3)+8*(r>>2)+4*hi]
#define LAYER(Wp, XIN, ACC)                                                                 \
    _Pragma("unroll")                                                                       \
    for (int nf = 0; nf < 8; nf++) {                                                        \
        ACC[nf] = (f32x16)(0.f);                                                            \
        _Pragma("unroll")                                                                   \
        for (int kb = 0; kb < 17; kb++) {                                                   \
            bf16x8 wf = *(const bf16x8*)((Wp) + (nf * 32 + l31) * WP + kb * 16 + hi * 8);   \
            ACC[nf] = __builtin_amdgcn_mfma_f32_32x32x16_bf16(wf, XIN[kb], ACC[nf], 0, 0, 0); \
        }                                                                                   \
    }

// repack acc (lane=data row m, regs=out-cols n) into next layer's B-fragments
// (lane=col m, k=hi*8+j). hi=0 lane holds n-offsets {0-3,8-11,16-19,24-27}; hi=1 +4.
// v_permlane32_swap_b32 vdst,vsrc: vdst upper-32 lanes <-> vsrc lower-32 lanes.
// => word needing PARTNER data in hi lanes = vdst (u0,u1,u4,u5);
//    word needing PARTNER data in lo lanes = vsrc (u2,u3,u6,u7).  [R14 had it reversed]
#define REPACK(ACC, XOUT)                                                                   \
    _Pragma("unroll")                                                                       \
    for (int nf = 0; nf < 8; nf++) {                                                        \
        float v[16];                                                                        \
        _Pragma("unroll")                                                                   \
        for (int r = 0; r < 16; r++) v[r] = fmaxf(ACC[nf][r], 0.f);                         \
        unsigned u0 = pk2(v[0], v[1]),   u1 = pk2(v[2], v[3]);                              \
        unsigned u2 = pk2(v[4], v[5]),   u3 = pk2(v[6], v[7]);                              \
        asm("v_permlane32_swap_b32 %0, %1" : "+v"(u0), "+v"(u2));                           \
        asm("v_permlane32_swap_b32 %0, %1" : "+v"(u1), "+v"(u3));                           \
        u32x4 wlo = {u0, u1, u2, u3};                                                       \
        XOUT[2 * nf] = __builtin_bit_cast(bf16x8, wlo);                                     \
        unsigned u4 = pk2(v[8], v[9]),   u5 = pk2(v[10], v[11]);                            \
        unsigned u6 = pk2(v[12], v[13]), u7 = pk2(v[14], v[15]);                            \
        asm("v_permlane32_swap_b32 %0, %1" : "+v"(u4), "+v"(u6));                           \
        asm("v_permlane32_swap_b32 %0, %1" : "+v"(u5), "+v"(u7));                           \
        u32x4 whi = {u4, u5, u6, u7};                                                       \
        XOUT[2 * nf + 1] = __builtin_bit_cast(bf16x8, whi);                                 \
    }

__global__ __launch_bounds__(256, 2)
void lte_msplit_kernel(const bf16_t* __restrict__ coefT,  // [4096][256] bf16
                       const bf16_t* __restrict__ freqT,  // [4096][128] bf16
                       const bf16_t* __restrict__ w1p,    // [256][272]
                       const bf16_t* __restrict__ w2p,
                       const bf16_t* __restrict__ w3p,    // [32][272]
                       const float4* __restrict__ wtab,   // [128]
                       const float* __restrict__ img,
                       const float* __restrict__ coord,
                       const float* __restrict__ cell,
                       float* __restrict__ out)
{
    __shared__ float sArea[4][32];
    __shared__ float sPreds[4][96];

    const int t    = threadIdx.x;
    const int lane = t & 63;
    const int wv   = t >> 6;
    const int l31  = lane & 31;
    const int hi   = lane >> 5;
    const int wgid = blockIdx.x * 4 + wv;   // global wave id: 32 rows, 8 queries
    const int row  = wgid * 32 + l31;
    const int q    = row >> 2;
    const int o    = row & 3;

    // ---- geometry (both lane-halves compute their row's geometry) ----
    const float c0  = coord[q * 2 + 0];
    const float c1  = coord[q * 2 + 1];
    const float rc0 = cell[q * 2 + 0] * (float)H;
    const float rc1 = cell[q * 2 + 1] * (float)W;
    const float vx = (o & 2) ? 1.f : -1.f;
    const float vy = (o & 1) ? 1.f : -1.f;
    const float EPS = 1e-6f;
    float g0 = fminf(fmaxf(c0 + vx * (1.f / H) + EPS, -1.f + EPS), 1.f - EPS);
    float g1 = fminf(fmaxf(c1 + vy * (1.f / W) + EPS, -1.f + EPS), 1.f - EPS);
    int iy = (int)floorf(((g0 + 1.f) * (float)H - 1.f) * 0.5f + 0.5f);
    iy = min(max(iy, 0), H - 1);
    int ix = (int)floorf(((g1 + 1.f) * (float)W - 1.f) * 0.5f + 0.5f);
    ix = min(max(ix, 0), W - 1);
    const float rel0 = (c0 - (-1.f + (2.f * (float)iy + 1.f) / (float)H)) * (float)H;
    const float rel1 = (c1 - (-1.f + (2.f * (float)ix + 1.f) / (float)W)) * (float)W;
    if (hi == 0) sArea[wv][l31] = fabsf(rel0 * rel1) + 1e-9f;
    const int pix = iy * W + ix;

    // ---- stage: X fragments straight into registers (no LDS) ----
    // frag xa[kb]: lane holds X[row][kb*16 + hi*8 + j]. kb<8 = cos half, kb+8 = sin half.
    bf16x8 xa[17];
    {
        const bf16_t* fq = freqT + pix * 128 + hi * 8;
        const bf16_t* cf = coefT + pix * 256 + hi * 8;
#pragma unroll
        for (int kb = 0; kb < 8; kb++) {
            bf16x8 fv = *(const bf16x8*)(fq + kb * 16);
            bf16x8 cc = *(const bf16x8*)(cf + kb * 16);
            bf16x8 cs = *(const bf16x8*)(cf + 128 + kb * 16);
            bf16x8 vc, vs;
#pragma unroll
            for (int j = 0; j < 8; j++) {
                const int k = kb * 16 + hi * 8 + j;
                const float4 tv = wtab[k];
                const float m = (float)fv[j] * (rel0 * tv.x + rel1 * tv.y) + (rc0 * tv.z + rc1 * tv.w);
                const float xr = __builtin_amdgcn_fractf(m * 0.5f);
                vc[j] = (bf16_t)((float)cc[j] * __builtin_amdgcn_cosf(xr));
                vs[j] = (bf16_t)((float)cs[j] * __builtin_amdgcn_sinf(xr));
            }
            xa[kb]     = vc;
            xa[kb + 8] = vs;
        }
    }
    // bias k-block: X[row][256] = 1 (k=256 lands at hi=0, j=0), rest 0
    {
        bf16x8 cfr;
#pragma unroll
        for (int j = 0; j < 8; j++) cfr[j] = (bf16_t)0.f;
        if (hi == 0) cfr[0] = (bf16_t)1.f;
        xa[16] = cfr;
    }

    // ---- layer 1 -> repack -> layer 2 -> repack (all in registers, no barriers) ----
    f32x16 acc[8];
    LAYER(w1p, xa, acc);
    REPACK(acc, xa);   // xa[16] (bias frag) unchanged
    LAYER(w2p, xa, acc);
    REPACK(acc, xa);

    // ---- layer 3: 17 MFMAs vs padded w3 (+b3 via bias col) ----
    f32x16 acc3 = (f32x16)(0.f);
#pragma unroll
    for (int kb = 0; kb < 17; kb++) {
        bf16x8 wf = *(const bf16x8*)(w3p + l31 * WP + kb * 16 + hi * 8);
        acc3 = __builtin_amdgcn_mfma_f32_32x32x16_bf16(wf, xa[kb], acc3, 0, 0, 0);
    }
    // acc3[r] = h3[data row m = l31][channel n = (r&3)+8*(r>>2)+4*hi]
    // channels 0..2 live at hi=0, r=0..2  [R14 had row/channel transposed]
    if (hi == 0) {
        sPreds[wv][l31 * 3 + 0] = acc3[0];
        sPreds[wv][l31 * 3 + 1] = acc3[1];
        sPreds[wv][l31 * 3 + 2] = acc3[2];
    }

    // ---- combine (wave-local: 8 queries x 3 channels on lanes 0..31) ----
    if (lane < 32 && (lane & 3) < 3) {
        const int qL = lane >> 2;       // 0..7
        const int ch = lane & 3;        // 0..2
        const int qg = wgid * 8 + qL;
        const int r0 = qL * 4;
        const float a0 = sArea[wv][r0 + 0], a1 = sArea[wv][r0 + 1];
        const float a2 = sArea[wv][r0 + 2], a3 = sArea[wv][r0 + 3];
        const float inv = 1.f / (a0 + a1 + a2 + a3);
        const float ret = sPreds[wv][(r0 + 0) * 3 + ch] * a3 * inv
                        + sPreds[wv][(r0 + 1) * 3 + ch] * a2 * inv
                        + sPreds[wv][(r0 + 2) * 3 + ch] * a1 * inv
                        + sPreds[wv][(r0 + 3) * 3 + ch] * a0 * inv;
        const float cc0 = coord[qg * 2 + 0];
        const float cc1 = coord[qg * 2 + 1];
        float gy = fminf(fmaxf(((cc0 + 1.f) * (float)H - 1.f) * 0.5f, 0.f), (float)(H - 1));
        float gx = fminf(fmaxf(((cc1 + 1.f) * (float)W - 1.f) * 0.5f, 0.f), (float)(W - 1));
        int y0 = (int)floorf(gy); int x0 = (int)floorf(gx);
        int y1 = min(y0 + 1, H - 1); int x1 = min(x0 + 1, W - 1);
        const float wy = gy - (float)y0, wx = gx - (float)x0;
        const float* ip = img + ch * 4096;
        const float samp = ip[y0 * 64 + x0] * (1.f - wy) * (1.f - wx)
                         + ip[y0 * 64 + x1] * (1.f - wy) * wx
                         + ip[y1 * 64 + x0] * wy * (1.f - wx)
                         + ip[y1 * 64 + x1] * wy * wx;
        out[qg * 3 + ch] = ret + samp;
    }
}

// ---------------- launch ----------------

extern "C" void kernel_launch(void* const* d_in, const int* in_sizes, int n_in,
                              void* d_out, int out_size, void* d_ws, size_t ws_size,
                              hipStream_t stream) {
    const float* img   = (const float*)d_in[0];
    const float* coef  = (const float*)d_in[1];
    const float* freq  = (const float*)d_in[2];
    const float* coord = (const float*)d_in[3];
    const float* cell  = (const float*)d_in[4];
    const float* wcf   = (const float*)d_in[5];
    const float* wph   = (const float*)d_in[6];
    const float* w1    = (const float*)d_in[7];
    const float* b1    = (const float*)d_in[8];
    const float* w2    = (const float*)d_in[9];
    const float* b2    = (const float*)d_in[10];
    const float* w3    = (const float*)d_in[11];
    const float* b3    = (const float*)d_in[12];
    float* out = (float*)d_out;

    char* ws = (char*)d_ws;
    bf16_t* coefT = (bf16_t*)ws;                  // 2,097,152
    bf16_t* freqT = (bf16_t*)(ws + 2097152);      // 1,048,576
    bf16_t* w1p   = (bf16_t*)(ws + 3145728);      // 139,264
    bf16_t* w2p   = (bf16_t*)(ws + 3284992);      // 139,264
    bf16_t* w3p   = (bf16_t*)(ws + 3424256);      // 17,408
    float4* wtab  = (float4*)(ws + 3441664);      // 2,048

    transpose_cvt_kernel<<<dim3(128, 8), 256, 0, stream>>>(coef, coefT, 256);
    transpose_cvt_kernel<<<dim3(128, 4), 256, 0, stream>>>(freq, freqT, 128);
    pack_tab_kernel<<<1, 128, 0, stream>>>(wcf, wph, wtab);
    build_wp_kernel<<<1, 256, 0, stream>>>(w1, b1, w2, b2, w3, b3, w1p, w2p, w3p);

    // 2048 blocks x 4 waves x 32 rows = 262144 rows
    lte_msplit_kernel<<<2048, 256, 0, stream>>>(
        coefT, freqT, w1p, w2p, w3p, wtab, img, coord, cell, out);
}

// Round 17
// 166.436 us; speedup vs baseline: 2.7166x; 2.7166x over previous
//
#include <hip/hip_runtime.h>
#include <math.h>

typedef __bf16 bf16_t;
typedef bf16_t bf16x8 __attribute__((ext_vector_type(8)));
typedef bf16_t bf16x4 __attribute__((ext_vector_type(4)));
typedef float  f32x4  __attribute__((ext_vector_type(4)));

constexpr int H = 64, W = 64, Q = 65536;
constexpr int C = 256, CF = 128;
constexpr int QPB = 32;        // queries per block -> 2048 blocks
constexpr int PADC = 264;      // LDS row stride (bf16)

// raw workgroup barrier: orders LDS (lgkmcnt) only; global register-destined
// prefetches (vmcnt) stay in flight across it. All cross-wave deps here are LDS.
#define BAR() asm volatile("s_waitcnt lgkmcnt(0)\n\ts_barrier" ::: "memory")

// ---------------- prep kernels ----------------

// src [Crows][4096] f32 -> dst [4096][Crows] bf16
__global__ void transpose_cvt_kernel(const float* __restrict__ src, bf16_t* __restrict__ dst, int Crows) {
    __shared__ float tile[32][33];
    int bx = blockIdx.x * 32;
    int by = blockIdx.y * 32;
    int tx = threadIdx.x & 31;
    int ty = threadIdx.x >> 5;
#pragma unroll
    for (int i = 0; i < 4; i++)
        tile[ty + i * 8][tx] = src[(by + ty + i * 8) * 4096 + bx + tx];
    __syncthreads();
#pragma unroll
    for (int i = 0; i < 4; i++)
        dst[(bx + ty + i * 8) * Crows + by + tx] = (bf16_t)tile[tx][ty + i * 8];
}

__global__ void cvt_w_kernel(const float* __restrict__ w1, const float* __restrict__ w2,
                             bf16_t* __restrict__ w1b, bf16_t* __restrict__ w2b) {
    int i = blockIdx.x * 256 + threadIdx.x;
    w1b[i] = (bf16_t)w1[i];
    w2b[i] = (bf16_t)w2[i];
}

__global__ void pack_tab_kernel(const float* __restrict__ wcf, const float* __restrict__ wph,
                                float4* __restrict__ wtab) {
    int k = threadIdx.x;
    float4 v;
    v.x = wcf[k * 2 + 0]; v.y = wcf[k * 2 + 1];
    v.z = wph[k * 2 + 0]; v.w = wph[k * 2 + 1];
    wtab[k] = v;
}

// w3 [3][256] -> w3p [16][256] bf16, rows 3..15 zero
__global__ void cvt_w3_kernel(const float* __restrict__ w3, bf16_t* __restrict__ w3p) {
    int k = threadIdx.x;
#pragma unroll
    for (int n = 0; n < 16; n++)
        w3p[n * 256 + k] = (n < 3) ? (bf16_t)w3[n * 256 + k] : (bf16_t)0.f;
}

// ---------------- fused main kernel (R13 + entry-prefetch + setprio) ----------------

// load the wave's 2 W-fragments for k-block kb (W rows = out-cols; A-fragment layout)
#define LOADB(dst, Wptr, kb)                                                                  \
    {                                                                                         \
        dst[0] = *(const bf16x8*)((Wptr) + (wv * 32 + l15) * 256 + (kb) * 32 + l16 * 8);      \
        dst[1] = *(const bf16x8*)((Wptr) + (wv * 32 + 16 + l15) * 256 + (kb) * 32 + l16 * 8); \
    }

__global__ __launch_bounds__(512, 4)
void lte_fused_kernel(const bf16_t* __restrict__ coefT,  // [4096][256] bf16
                      const bf16_t* __restrict__ freqT,  // [4096][128] bf16
                      const bf16_t* __restrict__ w1b,    // [256][256] (out,in)
                      const bf16_t* __restrict__ w2b,
                      const bf16_t* __restrict__ w3p,    // [16][256] padded bf16
                      const float4* __restrict__ wtab,   // [128] packed (wcf0,wcf1,wph0,wph1)
                      const float* __restrict__ img,     // [3][64][64]
                      const float* __restrict__ coord,   // [Q][2]
                      const float* __restrict__ cell,    // [Q][2]
                      const float* __restrict__ b1,
                      const float* __restrict__ b2,
                      const float* __restrict__ b3,
                      float* __restrict__ out)           // [Q][3]
{
    extern __shared__ char smem[];
    bf16_t* buf    = (bf16_t*)smem;              // [128][264] bf16: X -> h1 -> h2 (67584 B)
    float*  areaS  = (float*)(smem + 67584);     // [128]
    float*  predsS = (float*)(smem + 68096);     // [128][3]

    const int t    = threadIdx.x;
    const int lane = t & 63;
    const int wv   = t >> 6;     // wave id 0..7 -> 32-col stripe
    const int l15  = lane & 15;
    const int l16  = lane >> 4;

    // R17: issue layer-1 W prefetch at kernel ENTRY — latency hides under stage-1 trig
    bf16x8 b1q[8][2];
    LOADB(b1q[0], w1b, 0);
    LOADB(b1q[1], w1b, 1);

    // ---- stage 1: features -> X (bf16) in LDS. 4 threads/row, 32 k each ----
    {
        const int row = t >> 2;   // 0..127
        const int t4  = t & 3;
        const int qL  = row >> 2;
        const int o   = row & 3;
        const int q   = blockIdx.x * QPB + qL;
        const float c0  = coord[q * 2 + 0];
        const float c1  = coord[q * 2 + 1];
        const float rc0 = cell[q * 2 + 0] * (float)H;
        const float rc1 = cell[q * 2 + 1] * (float)W;
        const float vx = (o & 2) ? 1.f : -1.f;
        const float vy = (o & 1) ? 1.f : -1.f;
        const float EPS = 1e-6f;
        float g0 = fminf(fmaxf(c0 + vx * (1.f / H) + EPS, -1.f + EPS), 1.f - EPS);
        float g1 = fminf(fmaxf(c1 + vy * (1.f / W) + EPS, -1.f + EPS), 1.f - EPS);
        int iy = (int)floorf(((g0 + 1.f) * (float)H - 1.f) * 0.5f + 0.5f);
        iy = min(max(iy, 0), H - 1);
        int ix = (int)floorf(((g1 + 1.f) * (float)W - 1.f) * 0.5f + 0.5f);
        ix = min(max(ix, 0), W - 1);
        const float rel0 = (c0 - (-1.f + (2.f * (float)iy + 1.f) / (float)H)) * (float)H;
        const float rel1 = (c1 - (-1.f + (2.f * (float)ix + 1.f) / (float)W)) * (float)W;
        if (t4 == 0) areaS[row] = fabsf(rel0 * rel1) + 1e-9f;
        const int pix = iy * W + ix;
        const bf16_t* fq = freqT + pix * CF;
        const bf16_t* cf = coefT + pix * C;
        const int k0 = t4 * 32;

        // issue ALL gathers up front (12 x 16B)
        bf16x8 fqv[4], ccv[4], csv[4];
#pragma unroll
        for (int i = 0; i < 4; i++) {
            fqv[i] = *(const bf16x8*)(fq + k0 + i * 8);
            ccv[i] = *(const bf16x8*)(cf + k0 + i * 8);
            csv[i] = *(const bf16x8*)(cf + 128 + k0 + i * 8);
        }
#pragma unroll
        for (int i = 0; i < 4; i++) {
            bf16x8 vc, vs;
#pragma unroll
            for (int j = 0; j < 8; j++) {
                const int k = k0 + i * 8 + j;
                const float4 tv = wtab[k];
                const float proj = rel0 * tv.x + rel1 * tv.y;
                const float ph   = rc0 * tv.z + rc1 * tv.w;
                const float m = (float)fqv[i][j] * proj + ph;
                // sin(pi*m) = sin(2*pi*fract(m/2)) -- native HW trig
                const float xr  = __builtin_amdgcn_fractf(m * 0.5f);
                const float s   = __builtin_amdgcn_sinf(xr);
                const float cst = __builtin_amdgcn_cosf(xr);
                vc[j] = (bf16_t)((float)ccv[i][j] * cst);
                vs[j] = (bf16_t)((float)csv[i][j] * s);
            }
            *(bf16x8*)(buf + row * PADC + k0 + i * 8)       = vc;
            *(bf16x8*)(buf + row * PADC + 128 + k0 + i * 8) = vs;
        }
    }

    BAR();

    // ---- layer 1: swapped-operand MFMA: D = W_frag * X_frag (transposed C).
    //      Lane holds row = mi*16+l15, cols = wv*32+nf*16+l16*4..+3 -> b64 stores.
    bf16x8 b2q[8][2];
    {
        f32x4 acc[8][2];
#pragma unroll
        for (int mi = 0; mi < 8; mi++)
#pragma unroll
            for (int nf = 0; nf < 2; nf++) {
                f32x4 z = {0.f, 0.f, 0.f, 0.f};
                acc[mi][nf] = z;
            }
        __builtin_amdgcn_s_setprio(1);
#pragma unroll
        for (int kb = 0; kb < 8; kb++) {
            if (kb < 6) { LOADB(b1q[kb + 2], w1b, kb + 2); }
            bf16x8 a[8];
#pragma unroll
            for (int mi = 0; mi < 8; mi++)
                a[mi] = *(bf16x8*)(buf + (mi * 16 + l15) * PADC + kb * 32 + l16 * 8);
#pragma unroll
            for (int mi = 0; mi < 8; mi++)
#pragma unroll
                for (int nf = 0; nf < 2; nf++)
                    acc[mi][nf] = __builtin_amdgcn_mfma_f32_16x16x32_bf16(b1q[kb][nf], a[mi], acc[mi][nf], 0, 0, 0);
        }
        __builtin_amdgcn_s_setprio(0);
        // prefetch layer-2 kb=0,1 -- survives both raw barriers below
        LOADB(b2q[0], w2b, 0);
        LOADB(b2q[1], w2b, 1);
        BAR();  // all reads of X done
#pragma unroll
        for (int nf = 0; nf < 2; nf++) {
            const int colb = wv * 32 + nf * 16 + l16 * 4;
            const float4 bv = *(const float4*)(b1 + colb);
#pragma unroll
            for (int mi = 0; mi < 8; mi++) {
                const int row = mi * 16 + l15;
                bf16x4 h;
                h[0] = (bf16_t)fmaxf(acc[mi][nf][0] + bv.x, 0.f);
                h[1] = (bf16_t)fmaxf(acc[mi][nf][1] + bv.y, 0.f);
                h[2] = (bf16_t)fmaxf(acc[mi][nf][2] + bv.z, 0.f);
                h[3] = (bf16_t)fmaxf(acc[mi][nf][3] + bv.w, 0.f);
                *(bf16x4*)(buf + row * PADC + colb) = h;
            }
        }
        BAR();  // h1 visible
    }

    // ---- layer 2 (same swapped-operand scheme) ----
    {
        f32x4 acc[8][2];
#pragma unroll
        for (int mi = 0; mi < 8; mi++)
#pragma unroll
            for (int nf = 0; nf < 2; nf++) {
                f32x4 z = {0.f, 0.f, 0.f, 0.f};
                acc[mi][nf] = z;
            }
        __builtin_amdgcn_s_setprio(1);
#pragma unroll
        for (int kb = 0; kb < 8; kb++) {
            if (kb < 6) { LOADB(b2q[kb + 2], w2b, kb + 2); }
            bf16x8 a[8];
#pragma unroll
            for (int mi = 0; mi < 8; mi++)
                a[mi] = *(bf16x8*)(buf + (mi * 16 + l15) * PADC + kb * 32 + l16 * 8);
#pragma unroll
            for (int mi = 0; mi < 8; mi++)
#pragma unroll
                for (int nf = 0; nf < 2; nf++)
                    acc[mi][nf] = __builtin_amdgcn_mfma_f32_16x16x32_bf16(b2q[kb][nf], a[mi], acc[mi][nf], 0, 0, 0);
        }
        __builtin_amdgcn_s_setprio(0);
        BAR();  // all reads of h1 done
#pragma unroll
        for (int nf = 0; nf < 2; nf++) {
            const int colb = wv * 32 + nf * 16 + l16 * 4;
            const float4 bv = *(const float4*)(b2 + colb);
#pragma unroll
            for (int mi = 0; mi < 8; mi++) {
                const int row = mi * 16 + l15;
                bf16x4 h;
                h[0] = (bf16_t)fmaxf(acc[mi][nf][0] + bv.x, 0.f);
                h[1] = (bf16_t)fmaxf(acc[mi][nf][1] + bv.y, 0.f);
                h[2] = (bf16_t)fmaxf(acc[mi][nf][2] + bv.z, 0.f);
                h[3] = (bf16_t)fmaxf(acc[mi][nf][3] + bv.w, 0.f);
                *(bf16x4*)(buf + row * PADC + colb) = h;
            }
        }
        BAR();  // h2 visible
    }

    // ---- layer 3: MFMA vs padded w3 (conflict-free). wave wv = rows wv*16.. ----
    {
        f32x4 acc3 = {0.f, 0.f, 0.f, 0.f};
        __builtin_amdgcn_s_setprio(1);
#pragma unroll
        for (int kb = 0; kb < 8; kb++) {
            bf16x8 a = *(bf16x8*)(buf + (wv * 16 + l15) * PADC + kb * 32 + l16 * 8);
            bf16x8 b = *(const bf16x8*)(w3p + l15 * 256 + kb * 32 + l16 * 8);
            acc3 = __builtin_amdgcn_mfma_f32_16x16x32_bf16(a, b, acc3, 0, 0, 0);
        }
        __builtin_amdgcn_s_setprio(0);
        if (l15 < 3) {
            const float bv = b3[l15];
#pragma unroll
            for (int r = 0; r < 4; r++) {
                const int row = wv * 16 + l16 * 4 + r;
                predsS[row * 3 + l15] = acc3[r] + bv;
            }
        }
    }
    BAR();  // preds visible

    // ---- combine: area weights (reversed) + bilinear border sample ----
    if (t < QPB) {
        const int qL = t;
        const int q  = blockIdx.x * QPB + qL;
        const int r0 = qL * 4;
        const float a0 = areaS[r0 + 0], a1 = areaS[r0 + 1], a2 = areaS[r0 + 2], a3 = areaS[r0 + 3];
        const float inv = 1.f / (a0 + a1 + a2 + a3);
        const float wgt0 = a3 * inv, wgt1 = a2 * inv, wgt2 = a1 * inv, wgt3 = a0 * inv;
        const float c0 = coord[q * 2 + 0];
        const float c1 = coord[q * 2 + 1];
        float gy = fminf(fmaxf(((c0 + 1.f) * (float)H - 1.f) * 0.5f, 0.f), (float)(H - 1));
        float gx = fminf(fmaxf(((c1 + 1.f) * (float)W - 1.f) * 0.5f, 0.f), (float)(W - 1));
        int y0 = (int)floorf(gy); int x0 = (int)floorf(gx);
        int y1 = min(y0 + 1, H - 1); int x1 = min(x0 + 1, W - 1);
        const float wy = gy - (float)y0, wx = gx - (float)x0;
#pragma unroll
        for (int ch = 0; ch < 3; ch++) {
            const float ret = predsS[(r0 + 0) * 3 + ch] * wgt0 + predsS[(r0 + 1) * 3 + ch] * wgt1
                            + predsS[(r0 + 2) * 3 + ch] * wgt2 + predsS[(r0 + 3) * 3 + ch] * wgt3;
            const float* ip = img + ch * 4096;
            const float v00 = ip[y0 * 64 + x0], v01 = ip[y0 * 64 + x1];
            const float v10 = ip[y1 * 64 + x0], v11 = ip[y1 * 64 + x1];
            const float samp = v00 * (1.f - wy) * (1.f - wx) + v01 * (1.f - wy) * wx
                             + v10 * wy * (1.f - wx) + v11 * wy * wx;
            out[q * 3 + ch] = ret + samp;
        }
    }
}

// ---------------- launch ----------------

extern "C" void kernel_launch(void* const* d_in, const int* in_sizes, int n_in,
                              void* d_out, int out_size, void* d_ws, size_t ws_size,
                              hipStream_t stream) {
    const float* img   = (const float*)d_in[0];
    const float* coef  = (const float*)d_in[1];
    const float* freq  = (const float*)d_in[2];
    const float* coord = (const float*)d_in[3];
    const float* cell  = (const float*)d_in[4];
    const float* wcf   = (const float*)d_in[5];
    const float* wph   = (const float*)d_in[6];
    const float* w1    = (const float*)d_in[7];
    const float* b1    = (const float*)d_in[8];
    const float* w2    = (const float*)d_in[9];
    const float* b2    = (const float*)d_in[10];
    const float* w3    = (const float*)d_in[11];
    const float* b3    = (const float*)d_in[12];
    float* out = (float*)d_out;

    char* ws = (char*)d_ws;
    bf16_t* coefT = (bf16_t*)ws;                  // 2,097,152
    bf16_t* freqT = (bf16_t*)(ws + 2097152);      // 1,048,576
    bf16_t* w1b   = (bf16_t*)(ws + 3145728);      // 131,072
    bf16_t* w2b   = (bf16_t*)(ws + 3276800);      // 131,072
    float4* wtab  = (float4*)(ws + 3407872);      // 2,048
    bf16_t* w3p   = (bf16_t*)(ws + 3409920);      // 8,192

    transpose_cvt_kernel<<<dim3(128, 8), 256, 0, stream>>>(coef, coefT, 256);
    transpose_cvt_kernel<<<dim3(128, 4), 256, 0, stream>>>(freq, freqT, 128);
    cvt_w_kernel<<<256, 256, 0, stream>>>(w1, w2, w1b, w2b);
    pack_tab_kernel<<<1, 128, 0, stream>>>(wcf, wph, wtab);
    cvt_w3_kernel<<<1, 256, 0, stream>>>(w3, w3p);

    const size_t ldsBytes = 69632;  // 67584 buf + 512 area + 1536 preds
    lte_fused_kernel<<<Q / QPB, 512, ldsBytes, stream>>>(
        coefT, freqT, w1b, w2b, w3p, wtab, img, coord, cell, b1, b2, b3, out);
}